// Round 5
// baseline (416.861 us; speedup 1.0000x reference)
//
#include <hip/hip_runtime.h>
#include <hip/hip_bf16.h>
#include <math.h>

#define NT 365
#define NGRID 30000
#define NX 16
#define HID 256
#define CB 16   // cells per wave

typedef __attribute__((ext_vector_type(8))) short bf16x8;
typedef __attribute__((ext_vector_type(4))) float f32x4;

// HW packed f32->bf16 (RNE). 1 instr per 2 elements; inputs finite here.
static __device__ __forceinline__ unsigned cvt_pk(float lo, float hi) {
    unsigned r;
    asm("v_cvt_pk_bf16_f32 %0, %1, %2" : "=v"(r) : "v"(lo), "v"(hi));
    return r;
}

union BF8 { bf16x8 v; unsigned u[4]; };

static __device__ __forceinline__ short f2bf(float f) {   // setup only (cold)
    return __builtin_bit_cast(short, __float2bfloat16(f));
}

// Pre-kernel: w_eff = Wo@Wh (256), b_eff = Wo@bh + bo (scalar).
// ws layout: ws[0..255] = w_eff, ws[256] = b_eff.
__global__ void weff_kernel(const float* __restrict__ Wh, const float* __restrict__ Wo,
                            const float* __restrict__ bh, const float* __restrict__ bo,
                            float* __restrict__ ws) {
    int h = threadIdx.x;  // 256 threads
    float acc = 0.f;
    for (int j = 0; j < HID; ++j)
        acc = fmaf(Wo[j], Wh[j * HID + h], acc);
    ws[h] = acc;

    __shared__ float prod[HID];
    prod[h] = Wo[h] * bh[h];
    __syncthreads();
    if (h == 0) {
        float b = bo[0];
        for (int j = 0; j < HID; ++j) b += prod[j];
        ws[HID] = b;
    }
}

// One wave = 16 cells, no barriers, no shuffles (round-4 structure).
// MFMA-1 (x16): hidden layer; hidden rows permuted h(m,i)=32(m>>1)+8(i>>2)+4(m&1)+(i&3)
//   so C-layout output is directly MFMA-2's B fragment.
// MFMA-2 (2 independent 4-chains): A2 = w_eff broadcast rows -> result broadcast
//   to all lanes; b_eff via C-in. Hot-loop bf16 packing via v_cvt_pk_bf16_f32.
__global__ __launch_bounds__(64, 2) void rnn_mfma2(
    const float* __restrict__ x,   // (NT, NGRID, NX)
    const float* __restrict__ y,   // (NT, NGRID, 1), NaN = missing
    const float* __restrict__ Wi,  // (HID, NX+1)
    const float* __restrict__ bi,  // (HID)
    const float* __restrict__ ws,  // w_eff[256], b_eff
    float* __restrict__ out)       // (NT, NGRID, 1)
{
    const int lane = threadIdx.x & 63;
    const int c    = lane & 15;    // A-row / B-col / cell index
    const int hi   = lane >> 4;
    const int cell0 = blockIdx.x * CB;

    // ---- A1 fragments (Wi rows permuted by h(m,i)), resident ----
    bf16x8 a1[16];
#pragma unroll
    for (int m = 0; m < 16; ++m) {
        const int h = 32 * (m >> 1) + 8 * (c >> 2) + 4 * (m & 1) + (c & 3);
        const float* wrow = Wi + h * (NX + 1);
        bf16x8 av;
        if (hi < 2) {
#pragma unroll
            for (int j = 0; j < 8; ++j) av[j] = f2bf(wrow[hi * 8 + j]);
        } else if (hi == 2) {
            av[0] = f2bf(wrow[16]);            // k=16: weight on y_in
            av[1] = f2bf(bi[h]);               // k=17: bias (x const 1.0)
#pragma unroll
            for (int j = 2; j < 8; ++j) av[j] = 0;
        } else {
#pragma unroll
            for (int j = 0; j < 8; ++j) av[j] = 0;
        }
        a1[m] = av;
    }

    // ---- A2 fragments: w_eff, same value for all 16 rows ----
    bf16x8 a2[8];
#pragma unroll
    for (int ks = 0; ks < 8; ++ks) {
        bf16x8 av;
#pragma unroll
        for (int j = 0; j < 8; ++j) av[j] = f2bf(ws[32 * ks + 8 * hi + j]);
        a2[ks] = av;
    }
    const float b_eff = ws[HID];

    const size_t xoff = (size_t)(cell0 + c) * NX + hi * 8;
    const float* yb = y + cell0 + c;
    float*       ob = out + cell0 + c;

    // ---- depth-2 prefetch pipeline ----
    float4 xa_c = {0,0,0,0}, xb_c = {0,0,0,0};
    float4 xa_n = {0,0,0,0}, xb_n = {0,0,0,0};
    if (hi < 2) {
        const float4* p0 = (const float4*)(x + xoff);
        xa_c = p0[0]; xb_c = p0[1];
        const float4* p1 = (const float4*)(x + (size_t)NGRID * NX + xoff);
        xa_n = p1[0]; xb_n = p1[1];
    }
    float yo_c = yb[0];
    float yo_n = yb[NGRID];
    float yprev = 0.f;

    for (int t = 0; t < NT; ++t) {
        const float y_in = (yo_c == yo_c) ? yo_c : yprev;   // fillObs

        // ---- B1 fragment (HW packed cvt) ----
        BF8 b1;
        if (hi < 2) {
            b1.u[0] = cvt_pk(xa_c.x, xa_c.y);
            b1.u[1] = cvt_pk(xa_c.z, xa_c.w);
            b1.u[2] = cvt_pk(xb_c.x, xb_c.y);
            b1.u[3] = cvt_pk(xb_c.z, xb_c.w);
        } else if (hi == 2) {
            b1.u[0] = cvt_pk(y_in, 1.0f);                   // y slot + bias column
            b1.u[1] = 0; b1.u[2] = 0; b1.u[3] = 0;
        } else {
            b1.u[0] = 0; b1.u[1] = 0; b1.u[2] = 0; b1.u[3] = 0;
        }

        // issue prefetch for t+2 (lands ~2 steps later)
        float4 xa_f = xa_n, xb_f = xb_n;
        float yo_f = yo_n;
        if (t + 2 < NT) {
            if (hi < 2) {
                const float4* p = (const float4*)(x + (size_t)(t + 2) * NGRID * NX + xoff);
                xa_f = p[0]; xb_f = p[1];
            }
            yo_f = yb[(size_t)(t + 2) * NGRID];
        }

        // ---- hidden layer: 16 independent MFMAs ----
        const f32x4 zero4 = {0.f, 0.f, 0.f, 0.f};
        f32x4 acc1[16];
#pragma unroll
        for (int m = 0; m < 16; ++m)
            acc1[m] = __builtin_amdgcn_mfma_f32_16x16x32_bf16(a1[m], b1.v, zero4, 0, 0, 0);

        // ---- relu + pack as B2 fragments: 32 max + 16 cvt_pk ----
        BF8 b2[8];
#pragma unroll
        for (int ks = 0; ks < 8; ++ks) {
            const f32x4 e = acc1[2 * ks], o = acc1[2 * ks + 1];
            b2[ks].u[0] = cvt_pk(fmaxf(e[0], 0.f), fmaxf(e[1], 0.f));
            b2[ks].u[1] = cvt_pk(fmaxf(e[2], 0.f), fmaxf(e[3], 0.f));
            b2[ks].u[2] = cvt_pk(fmaxf(o[0], 0.f), fmaxf(o[1], 0.f));
            b2[ks].u[3] = cvt_pk(fmaxf(o[2], 0.f), fmaxf(o[3], 0.f));
        }

        // ---- output projection: two independent 4-deep MFMA chains ----
        f32x4 accA = {b_eff, b_eff, b_eff, b_eff};
        f32x4 accB = zero4;
#pragma unroll
        for (int q = 0; q < 4; ++q) {
            accA = __builtin_amdgcn_mfma_f32_16x16x32_bf16(a2[2 * q],     b2[2 * q].v,     accA, 0, 0, 0);
            accB = __builtin_amdgcn_mfma_f32_16x16x32_bf16(a2[2 * q + 1], b2[2 * q + 1].v, accB, 0, 0, 0);
        }

        const float ynew = accA[0] + accB[0];  // z[c]+b_eff, broadcast in every lane

        if (lane < 16) ob[(size_t)t * NGRID] = ynew;
        yprev = ynew;

        // rotate prefetch buffers
        xa_c = xa_n; xb_c = xb_n; yo_c = yo_n;
        xa_n = xa_f; xb_n = xb_f; yo_n = yo_f;
    }
}

extern "C" void kernel_launch(void* const* d_in, const int* in_sizes, int n_in,
                              void* d_out, int out_size, void* d_ws, size_t ws_size,
                              hipStream_t stream) {
    const float* x  = (const float*)d_in[0];
    const float* y  = (const float*)d_in[1];
    const float* Wi = (const float*)d_in[2];
    const float* bi = (const float*)d_in[3];
    const float* Wh = (const float*)d_in[4];
    const float* bh = (const float*)d_in[5];
    const float* Wo = (const float*)d_in[6];
    const float* bo = (const float*)d_in[7];
    float* out = (float*)d_out;
    float* ws  = (float*)d_ws;

    weff_kernel<<<1, HID, 0, stream>>>(Wh, Wo, bh, bo, ws);
    rnn_mfma2<<<NGRID / CB, 64, 0, stream>>>(x, y, Wi, bi, ws, out);
}